// Round 3
// baseline (4394.830 us; speedup 1.0000x reference)
//
#include <hip/hip_runtime.h>
#include <math.h>

// Mesh encoder: 4x (spiral conv + ELU + sparse pool) + final GEMM.
// VERTS = [65536, 16384, 4096, 1024, 256], SEQ=9, CH=[3,32,64,128,256], B=16.
//
// Zero hot-path atomics: per-call device-built CSR (start/perm, cnt-sorted
// row order), fused row-parallel conv+pool for L0/L1, edge-parallel conv +
// coalesced gather for L2/L3. Activations in [V][C][16] layout.

#define SEQL 9

__device__ __forceinline__ void fma4(float4& a, float s, const float4& w) {
    a.x = fmaf(s, w.x, a.x); a.y = fmaf(s, w.y, a.y);
    a.z = fmaf(s, w.z, a.z); a.w = fmaf(s, w.w, a.w);
}
__device__ __forceinline__ float elu1(float y) {
    return y > 0.0f ? y : __expf(y) - 1.0f;
}
__device__ __forceinline__ float getc(const float4& v, int i) {
    switch (i) { case 0: return v.x; case 1: return v.y; case 2: return v.z; default: return v.w; }
}

// ---------- builders ----------

// x [16][65536][3] -> xT [65536][3][16]
__global__ __launch_bounds__(256)
void transpose_x0(const float* __restrict__ x, float* __restrict__ xT)
{
    const int f = blockIdx.x * 256 + threadIdx.x;   // 65536*48
    const int v = f / 48, rem = f % 48;
    const int c = rem / 16, b = rem % 16;
    xT[f] = x[((size_t)b * 65536 + v) * 3 + c];
}

__global__ __launch_bounds__(256)
void hist_edges(const int* __restrict__ r0, const int* __restrict__ r1,
                const int* __restrict__ r2, const int* __restrict__ r3,
                int* c0, int* c1, int* c2, int* c3)
{
    const int g = blockIdx.x * 256 + threadIdx.x;
    if (g < 49152)      atomicAdd(&c0[r0[g]], 1);
    else if (g < 61440) atomicAdd(&c1[r1[g - 49152]], 1);
    else if (g < 64512) atomicAdd(&c2[r2[g - 61440]], 1);
    else if (g < 65280) atomicAdd(&c3[r3[g - 64512]], 1);
}

struct ScanTasks { const int* in[6]; int* out[6]; int n[6]; };

__global__ __launch_bounds__(256)
void scan_multi(ScanTasks T, int first)
{
    const int* in = T.in[first + blockIdx.x];
    int*       out = T.out[first + blockIdx.x];
    const int  n = T.n[first + blockIdx.x];
    __shared__ int lds[256];
    const int tid = threadIdx.x;
    const int chunk = (n + 255) / 256;
    const int base = tid * chunk;
    int s = 0;
    for (int i = 0; i < chunk; ++i) { int p = base + i; if (p < n) s += in[p]; }
    lds[tid] = s; __syncthreads();
    int acc = s;
    for (int off = 1; off < 256; off <<= 1) {
        int t = (tid >= off) ? lds[tid - off] : 0;
        __syncthreads();
        acc += t; lds[tid] = acc;
        __syncthreads();
    }
    int run = acc - s;   // exclusive prefix
    for (int i = 0; i < chunk; ++i) { int p = base + i; if (p < n) { out[p] = run; run += in[p]; } }
    if (tid == 255) out[n] = run;
}

__global__ __launch_bounds__(256)
void scatter_edges(const int* __restrict__ r0, const int* __restrict__ r1,
                   const int* __restrict__ r2, const int* __restrict__ r3,
                   const int* s0, const int* s1, const int* s2, const int* s3,
                   int* u0, int* u1, int* u2, int* u3,
                   int* p0, int* p1, int* p2, int* p3)
{
    const int g = blockIdx.x * 256 + threadIdx.x;
    if (g < 49152)      { int k = g;         int r = r0[k]; p0[s0[r] + atomicAdd(&u0[r], 1)] = k; }
    else if (g < 61440) { int k = g - 49152; int r = r1[k]; p1[s1[r] + atomicAdd(&u1[r], 1)] = k; }
    else if (g < 64512) { int k = g - 61440; int r = r2[k]; p2[s2[r] + atomicAdd(&u2[r], 1)] = k; }
    else if (g < 65280) { int k = g - 64512; int r = r3[k]; p3[s3[r] + atomicAdd(&u3[r], 1)] = k; }
}

__global__ __launch_bounds__(256)
void sort_hist(const int* __restrict__ s0, const int* __restrict__ s1,
               int* bn0, int* bn1)
{
    const int g = blockIdx.x * 256 + threadIdx.x;
    if (g < 16384)      { int c = s0[g + 1] - s0[g]; atomicAdd(&bn0[c > 63 ? 63 : c], 1); }
    else if (g < 20480) { int r = g - 16384; int c = s1[r + 1] - s1[r]; atomicAdd(&bn1[c > 63 ? 63 : c], 1); }
}

__global__ __launch_bounds__(256)
void sort_scatter(const int* __restrict__ s0, const int* __restrict__ s1,
                  const int* __restrict__ t0, const int* __restrict__ t1,
                  int* bc0, int* bc1, int* ro0, int* ro1)
{
    const int g = blockIdx.x * 256 + threadIdx.x;
    if (g < 16384)      { int c = s0[g + 1] - s0[g]; c = c > 63 ? 63 : c; ro0[t0[c] + atomicAdd(&bc0[c], 1)] = g; }
    else if (g < 20480) { int r = g - 16384; int c = s1[r + 1] - s1[r]; c = c > 63 ? 63 : c; ro1[t1[c] + atomicAdd(&bc1[c], 1)] = r; }
}

// ---------- fused conv+ELU+pool (L0, L1): R parallel rows, sequential edges ----------
// thread: cq = tid % CL (co-quad), bh = (tid/CL)&1 (batch half), lr = tid/(2CL) (local row)
template<int CIN, int COUT, int R>
__global__ __launch_bounds__(256)
void fused_conv_pool(const float* __restrict__ xT,   // [NV][CIN][16]
                     const int* __restrict__ idx,    // [NV][9]
                     const int* __restrict__ col, const float* __restrict__ val,
                     const int* __restrict__ start, const int* __restrict__ perm,
                     const int* __restrict__ row_order,
                     const float* __restrict__ W,    // [9*CIN][COUT]
                     const float* __restrict__ bias,
                     float* __restrict__ out)        // [NVOUT][COUT][16]
{
    constexpr int CL = COUT / 4;
    static_assert(R * CL * 2 == 256, "bad geometry");
    constexpr int SLICE  = CIN * 16;
    constexpr int PAD    = (CIN == 3) ? 12 : 4;
    constexpr int STRIDE = SLICE + PAD;
    constexpr int NF4    = R * CIN * 4;
    constexpr int NIT    = (NF4 + 255) / 256;

    __shared__ float xg[R * STRIDE];
    __shared__ int   sv[R][9];
    __shared__ int   srow[R], sstart[R], scnt[R];
    __shared__ float sval[R];

    const int tid = threadIdx.x;
    const int cq = tid % CL;
    const int bh = (tid / CL) & 1;
    const int lr = tid / (CL * 2);

    if (tid < R) {
        int r = row_order[blockIdx.x * R + tid];
        srow[tid] = r;
        int a = start[r];
        sstart[tid] = a; scnt[tid] = start[r + 1] - a;
    }
    __syncthreads();
    const int maxcnt = scnt[R - 1];   // rows cnt-sorted ascending -> last is max

    const float4 bias4 = *(const float4*)(bias + 4 * cq);
    float4 pacc[8];
#pragma unroll
    for (int b = 0; b < 8; ++b) pacc[b] = make_float4(0.f, 0.f, 0.f, 0.f);

    for (int j = 0; j < maxcnt; ++j) {
        if (tid < R) {
            bool vld = j < scnt[tid];
            int e = vld ? perm[sstart[tid] + j] : 0;
            sval[tid] = vld ? val[e] : 0.0f;
            int cv = col[e];
#pragma unroll
            for (int s = 0; s < SEQL; ++s) sv[tid][s] = idx[cv * SEQL + s];
        }
        __syncthreads();

        float4 cacc[8];
#pragma unroll
        for (int b = 0; b < 8; ++b) cacc[b] = bias4;

        for (int s = 0; s < SEQL; ++s) {
#pragma unroll
            for (int it = 0; it < NIT; ++it) {
                int f = tid + it * 256;
                if (NF4 % 256 == 0 || f < NF4) {
                    int fe = f / (CIN * 4), fr = f % (CIN * 4);
                    float4 t = *(const float4*)(xT + (size_t)sv[fe][s] * SLICE + fr * 4);
                    *(float4*)(xg + fe * STRIDE + fr * 4) = t;
                }
            }
            __syncthreads();
            const float* xb = xg + lr * STRIDE + bh * 8;
            const float* Wp = W + (size_t)(s * CIN) * COUT + 4 * cq;
#pragma unroll
            for (int c = 0; c < CIN; ++c) {
                float4 w  = *(const float4*)(Wp + (size_t)c * COUT);
                float4 x0 = *(const float4*)(xb + c * 16);
                float4 x1 = *(const float4*)(xb + c * 16 + 4);
                fma4(cacc[0], x0.x, w); fma4(cacc[1], x0.y, w);
                fma4(cacc[2], x0.z, w); fma4(cacc[3], x0.w, w);
                fma4(cacc[4], x1.x, w); fma4(cacc[5], x1.y, w);
                fma4(cacc[6], x1.z, w); fma4(cacc[7], x1.w, w);
            }
            if (s < SEQL - 1) __syncthreads();   // WAR on xg
        }
        // pool: pacc += val * elu(conv)
        const float vv = sval[lr];
#pragma unroll
        for (int b = 0; b < 8; ++b) {
            float4 y = cacc[b];
            y.x = elu1(y.x); y.y = elu1(y.y); y.z = elu1(y.z); y.w = elu1(y.w);
            fma4(pacc[b], vv, y);
        }
        __syncthreads();   // sval/sv/xg reuse next j
    }

    const int r = srow[lr];
    float* op = out + ((size_t)r * COUT + 4 * cq) * 16 + bh * 8;
#pragma unroll
    for (int i = 0; i < 4; ++i)
#pragma unroll
        for (int q = 0; q < 2; ++q) {
            float4 o = make_float4(getc(pacc[4 * q + 0], i), getc(pacc[4 * q + 1], i),
                                   getc(pacc[4 * q + 2], i), getc(pacc[4 * q + 3], i));
            *(float4*)(op + (size_t)i * 16 + q * 4) = o;
        }
}

// ---------- edge-parallel conv+ELU+scale (L2, L3) -> ye[k][COUT][16] ----------
template<int CIN, int COUT, int EPB>
__global__ __launch_bounds__(256)
void conv_edges(const float* __restrict__ xT, const int* __restrict__ idx,
                const int* __restrict__ col, const float* __restrict__ val,
                const float* __restrict__ W, const float* __restrict__ bias,
                float* __restrict__ ye)
{
    constexpr int CL = COUT / 4;
    static_assert(EPB * CL == 256, "bad geometry");
    constexpr int SLICE  = CIN * 16;
    constexpr int STRIDE = CIN * 8 + 4;
    constexpr int NF4    = EPB * CIN * 2;
    constexpr int NIT    = (NF4 + 255) / 256;

    __shared__ float xg[EPB * STRIDE];
    __shared__ int   sv[EPB][9];

    const int tid = threadIdx.x;
    const int cq = tid % CL;
    const int e  = tid / CL;
    const int k0 = blockIdx.x * EPB;
    const int bh0 = blockIdx.y * 8;

    if (tid < EPB) {
        int cv = col[k0 + tid];
#pragma unroll
        for (int s = 0; s < SEQL; ++s) sv[tid][s] = idx[cv * SEQL + s];
    }
    __syncthreads();

    const float4 bias4 = *(const float4*)(bias + 4 * cq);
    float4 cacc[8];
#pragma unroll
    for (int b = 0; b < 8; ++b) cacc[b] = bias4;

    for (int s = 0; s < SEQL; ++s) {
#pragma unroll
        for (int it = 0; it < NIT; ++it) {
            int f = tid + it * 256;
            if (NF4 % 256 == 0 || f < NF4) {
                int fe = f / (CIN * 2), fr = f % (CIN * 2);
                int c = fr >> 1, q = fr & 1;
                float4 t = *(const float4*)(xT + (size_t)sv[fe][s] * SLICE + c * 16 + bh0 + q * 4);
                *(float4*)(xg + fe * STRIDE + fr * 4) = t;
            }
        }
        __syncthreads();
        const float* xb = xg + e * STRIDE;
        const float* Wp = W + (size_t)(s * CIN) * COUT + 4 * cq;
#pragma unroll
        for (int c = 0; c < CIN; ++c) {
            float4 w  = *(const float4*)(Wp + (size_t)c * COUT);
            float4 x0 = *(const float4*)(xb + c * 8);
            float4 x1 = *(const float4*)(xb + c * 8 + 4);
            fma4(cacc[0], x0.x, w); fma4(cacc[1], x0.y, w);
            fma4(cacc[2], x0.z, w); fma4(cacc[3], x0.w, w);
            fma4(cacc[4], x1.x, w); fma4(cacc[5], x1.y, w);
            fma4(cacc[6], x1.z, w); fma4(cacc[7], x1.w, w);
        }
        if (s < SEQL - 1) __syncthreads();
    }

    const float vv = val[k0 + e];
#pragma unroll
    for (int b = 0; b < 8; ++b) {
        float4 y = cacc[b];
        cacc[b] = make_float4(vv * elu1(y.x), vv * elu1(y.y), vv * elu1(y.z), vv * elu1(y.w));
    }
    float* yp = ye + ((size_t)(k0 + e) * COUT + 4 * cq) * 16 + bh0;
#pragma unroll
    for (int i = 0; i < 4; ++i)
#pragma unroll
        for (int q = 0; q < 2; ++q) {
            float4 o = make_float4(getc(cacc[4 * q + 0], i), getc(cacc[4 * q + 1], i),
                                   getc(cacc[4 * q + 2], i), getc(cacc[4 * q + 3], i));
            *(float4*)(yp + (size_t)i * 16 + q * 4) = o;
        }
}

// ---------- CSR gather pool (L2, L3): out[r] = sum_j ye[perm[j]] ----------
template<int COUT>
__global__ __launch_bounds__(256)
void pool_gather(const float* __restrict__ ye, const int* __restrict__ start,
                 const int* __restrict__ perm, float* __restrict__ out)
{
    constexpr int RW = COUT * 4;   // float4s per out row
    const int pos = blockIdx.x * 256 + threadIdx.x;
    const int r = pos / RW, o = pos % RW;
    const int lo = start[r], hi = start[r + 1];
    float4 a = make_float4(0.f, 0.f, 0.f, 0.f);
    for (int j = lo; j < hi; ++j) {
        int e = perm[j];
        float4 y = *(const float4*)(ye + (size_t)e * RW * 4 + o * 4);
        a.x += y.x; a.y += y.y; a.z += y.z; a.w += y.w;   // val already folded into ye
    }
    *(float4*)(out + (size_t)r * RW * 4 + o * 4) = a;
}

// ---------- final GEMM ----------
__global__ __launch_bounds__(256)
void final_gemm_partial(const float* __restrict__ x4T,  // [65536][16] (vert,co major)
                        const float* __restrict__ Wf,   // [65536][256]
                        float* __restrict__ part)       // [256][16][256]
{
    __shared__ float xs[256 * 16];
    const int j0 = blockIdx.x * 256;
    const int t  = threadIdx.x;
#pragma unroll
    for (int it = 0; it < 4; ++it) {
        const int f = t + it * 256;
        *(float4*)(xs + f * 4) = *(const float4*)(x4T + (size_t)j0 * 16 + f * 4);
    }
    __syncthreads();

    float acc[16];
#pragma unroll
    for (int b = 0; b < 16; ++b) acc[b] = 0.0f;
#pragma unroll 4
    for (int jj = 0; jj < 256; ++jj) {
        const float w = Wf[(size_t)(j0 + jj) * 256 + t];
#pragma unroll
        for (int b4 = 0; b4 < 4; ++b4) {
            const float4 xv = *(const float4*)(xs + jj * 16 + b4 * 4);
            acc[b4 * 4 + 0] = fmaf(xv.x, w, acc[b4 * 4 + 0]);
            acc[b4 * 4 + 1] = fmaf(xv.y, w, acc[b4 * 4 + 1]);
            acc[b4 * 4 + 2] = fmaf(xv.z, w, acc[b4 * 4 + 2]);
            acc[b4 * 4 + 3] = fmaf(xv.w, w, acc[b4 * 4 + 3]);
        }
    }
#pragma unroll
    for (int b = 0; b < 16; ++b)
        part[(size_t)blockIdx.x * 4096 + b * 256 + t] = acc[b];
}

__global__ __launch_bounds__(256)
void final_reduce(const float* __restrict__ part, const float* __restrict__ bf,
                  float* __restrict__ out)
{
    const int b = blockIdx.x, l = threadIdx.x;
    float s = 0.0f;
    for (int jb = 0; jb < 256; ++jb) s += part[(size_t)jb * 4096 + b * 256 + l];
    out[b * 256 + l] = s + bf[l];
}

// ---------- launch ----------
extern "C" void kernel_launch(void* const* d_in, const int* in_sizes, int n_in,
                              void* d_out, int out_size, void* d_ws, size_t ws_size,
                              hipStream_t stream)
{
    const float* x    = (const float*)d_in[0];
    const int*   idx0 = (const int*)d_in[1];
    const int*   row0 = (const int*)d_in[2];
    const int*   col0 = (const int*)d_in[3];
    const float* val0 = (const float*)d_in[4];
    const float* W0   = (const float*)d_in[5];
    const float* b0   = (const float*)d_in[6];
    const int*   idx1 = (const int*)d_in[7];
    const int*   row1 = (const int*)d_in[8];
    const int*   col1 = (const int*)d_in[9];
    const float* val1 = (const float*)d_in[10];
    const float* W1   = (const float*)d_in[11];
    const float* b1   = (const float*)d_in[12];
    const int*   idx2 = (const int*)d_in[13];
    const int*   row2 = (const int*)d_in[14];
    const int*   col2 = (const int*)d_in[15];
    const float* val2 = (const float*)d_in[16];
    const float* W2   = (const float*)d_in[17];
    const float* b2   = (const float*)d_in[18];
    const int*   idx3 = (const int*)d_in[19];
    const int*   row3 = (const int*)d_in[20];
    const int*   col3 = (const int*)d_in[21];
    const float* val3 = (const float*)d_in[22];
    const float* W3   = (const float*)d_in[23];
    const float* b3   = (const float*)d_in[24];
    const float* Wf   = (const float*)d_in[25];
    const float* bf   = (const float*)d_in[26];
    float* out = (float*)d_out;

    float* ws = (float*)d_ws;
    // activation aliasing (float offsets), lifetimes verified disjoint:
    float* x1T = ws + 0;          // [16384][32][16]  P1-P2
    float* xT0 = ws + 8388608;    // [65536][3][16]   P0-P1
    float* x2T = ws + 8388608;    // [4096][64][16]   P2-P3 (over dead xT0)
    float* ye2 = ws + 0;          // [3072][128][16]  P3-P4 (over dead x1T)
    float* x3T = ws + 6291456;    // [1024][128][16]  P4-P5
    float* ye3 = ws + 0;          // [768][256][16]   P5-P6
    float* x4T = ws + 3145728;    // [256][256][16]   P6-P7
    float* part= ws + 4194304;    // [256][16][256]   P7

    int* csr = (int*)(ws + 12582912);
    int *c0 = csr +      0, *c1 = csr + 16384, *c2 = csr + 20480, *c3 = csr + 21504;
    int *u0 = csr +  21760, *u1 = csr + 38144, *u2 = csr + 42240, *u3 = csr + 43264;
    int *bn0= csr +  43520, *bn1= csr + 43584;
    int *bc0= csr +  43648, *bc1= csr + 43712;
    int *s0 = csr +  43776, *s1 = csr + 60161, *s2 = csr + 64258, *s3 = csr + 65283;
    int *t0 = csr +  65540, *t1 = csr + 65605;
    int *p0 = csr +  65670, *p1 = csr + 114822, *p2 = csr + 127110, *p3 = csr + 130182;
    int *ro0= csr + 130950, *ro1= csr + 147334;

    // zero counts/cursors/bins/bincursors in one memset
    hipMemsetAsync(csr, 0, (size_t)43776 * sizeof(int), stream);

    transpose_x0<<<12288, 256, 0, stream>>>(x, xT0);

    hist_edges<<<255, 256, 0, stream>>>(row0, row1, row2, row3, c0, c1, c2, c3);

    ScanTasks T;
    T.in[0]=c0; T.out[0]=s0; T.n[0]=16384;
    T.in[1]=c1; T.out[1]=s1; T.n[1]=4096;
    T.in[2]=c2; T.out[2]=s2; T.n[2]=1024;
    T.in[3]=c3; T.out[3]=s3; T.n[3]=256;
    T.in[4]=bn0;T.out[4]=t0; T.n[4]=64;
    T.in[5]=bn1;T.out[5]=t1; T.n[5]=64;
    scan_multi<<<4, 256, 0, stream>>>(T, 0);

    scatter_edges<<<255, 256, 0, stream>>>(row0, row1, row2, row3,
                                           s0, s1, s2, s3, u0, u1, u2, u3,
                                           p0, p1, p2, p3);
    sort_hist<<<80, 256, 0, stream>>>(s0, s1, bn0, bn1);
    scan_multi<<<2, 256, 0, stream>>>(T, 4);
    sort_scatter<<<80, 256, 0, stream>>>(s0, s1, t0, t1, bc0, bc1, ro0, ro1);

    // L0: xT0 -> x1T
    fused_conv_pool<3, 32, 16><<<1024, 256, 0, stream>>>(
        xT0, idx0, col0, val0, s0, p0, ro0, W0, b0, x1T);
    // L1: x1T -> x2T
    fused_conv_pool<32, 64, 8><<<512, 256, 0, stream>>>(
        x1T, idx1, col1, val1, s1, p1, ro1, W1, b1, x2T);
    // L2: x2T -> ye2 -> x3T
    conv_edges<64, 128, 8><<<dim3(384, 2), 256, 0, stream>>>(
        x2T, idx2, col2, val2, W2, b2, ye2);
    pool_gather<128><<<2048, 256, 0, stream>>>(ye2, s2, p2, x3T);
    // L3: x3T -> ye3 -> x4T
    conv_edges<128, 256, 4><<<dim3(192, 2), 256, 0, stream>>>(
        x3T, idx3, col3, val3, W3, b3, ye3);
    pool_gather<256><<<1024, 256, 0, stream>>>(ye3, s3, p3, x4T);

    // final GEMM
    final_gemm_partial<<<256, 256, 0, stream>>>(x4T, Wf, part);
    final_reduce<<<16, 256, 0, stream>>>(part, bf, out);
}

// Round 4
// 1155.779 us; speedup vs baseline: 3.8025x; 3.8025x over previous
//
#include <hip/hip_runtime.h>
#include <math.h>

// Mesh encoder: 4x (spiral conv + ELU + sparse pool) + final GEMM.
// VERTS = [65536, 16384, 4096, 1024, 256], SEQ=9, CH=[3,32,64,128,256], B=16.
//
// Zero hot-path atomics: per-call device-built CSR (start/perm, cnt-sorted
// row order), fused row-parallel conv+pool for L0/L1, edge-parallel conv +
// coalesced gather for L2/L3. Activations in [V][C][16] layout.
// R3->R4: cap c-loop unroll at 2 for CIN>=32 (R3 fully unrolled -> 256 VGPR
// + scratch spill, 3.7GB spill writes on conv_edges).

#define SEQL 9

__device__ __forceinline__ void fma4(float4& a, float s, const float4& w) {
    a.x = fmaf(s, w.x, a.x); a.y = fmaf(s, w.y, a.y);
    a.z = fmaf(s, w.z, a.z); a.w = fmaf(s, w.w, a.w);
}
__device__ __forceinline__ float elu1(float y) {
    return y > 0.0f ? y : __expf(y) - 1.0f;
}
__device__ __forceinline__ float getc(const float4& v, int i) {
    switch (i) { case 0: return v.x; case 1: return v.y; case 2: return v.z; default: return v.w; }
}

// ---------- builders ----------

// x [16][65536][3] -> xT [65536][3][16]
__global__ __launch_bounds__(256)
void transpose_x0(const float* __restrict__ x, float* __restrict__ xT)
{
    const int f = blockIdx.x * 256 + threadIdx.x;   // 65536*48
    const int v = f / 48, rem = f % 48;
    const int c = rem / 16, b = rem % 16;
    xT[f] = x[((size_t)b * 65536 + v) * 3 + c];
}

__global__ __launch_bounds__(256)
void hist_edges(const int* __restrict__ r0, const int* __restrict__ r1,
                const int* __restrict__ r2, const int* __restrict__ r3,
                int* c0, int* c1, int* c2, int* c3)
{
    const int g = blockIdx.x * 256 + threadIdx.x;
    if (g < 49152)      atomicAdd(&c0[r0[g]], 1);
    else if (g < 61440) atomicAdd(&c1[r1[g - 49152]], 1);
    else if (g < 64512) atomicAdd(&c2[r2[g - 61440]], 1);
    else if (g < 65280) atomicAdd(&c3[r3[g - 64512]], 1);
}

struct ScanTasks { const int* in[6]; int* out[6]; int n[6]; };

__global__ __launch_bounds__(256)
void scan_multi(ScanTasks T, int first)
{
    const int* in = T.in[first + blockIdx.x];
    int*       out = T.out[first + blockIdx.x];
    const int  n = T.n[first + blockIdx.x];
    __shared__ int lds[256];
    const int tid = threadIdx.x;
    const int chunk = (n + 255) / 256;
    const int base = tid * chunk;
    int s = 0;
    for (int i = 0; i < chunk; ++i) { int p = base + i; if (p < n) s += in[p]; }
    lds[tid] = s; __syncthreads();
    int acc = s;
    for (int off = 1; off < 256; off <<= 1) {
        int t = (tid >= off) ? lds[tid - off] : 0;
        __syncthreads();
        acc += t; lds[tid] = acc;
        __syncthreads();
    }
    int run = acc - s;   // exclusive prefix
    for (int i = 0; i < chunk; ++i) { int p = base + i; if (p < n) { out[p] = run; run += in[p]; } }
    if (tid == 255) out[n] = run;
}

__global__ __launch_bounds__(256)
void scatter_edges(const int* __restrict__ r0, const int* __restrict__ r1,
                   const int* __restrict__ r2, const int* __restrict__ r3,
                   const int* s0, const int* s1, const int* s2, const int* s3,
                   int* u0, int* u1, int* u2, int* u3,
                   int* p0, int* p1, int* p2, int* p3)
{
    const int g = blockIdx.x * 256 + threadIdx.x;
    if (g < 49152)      { int k = g;         int r = r0[k]; p0[s0[r] + atomicAdd(&u0[r], 1)] = k; }
    else if (g < 61440) { int k = g - 49152; int r = r1[k]; p1[s1[r] + atomicAdd(&u1[r], 1)] = k; }
    else if (g < 64512) { int k = g - 61440; int r = r2[k]; p2[s2[r] + atomicAdd(&u2[r], 1)] = k; }
    else if (g < 65280) { int k = g - 64512; int r = r3[k]; p3[s3[r] + atomicAdd(&u3[r], 1)] = k; }
}

__global__ __launch_bounds__(256)
void sort_hist(const int* __restrict__ s0, const int* __restrict__ s1,
               int* bn0, int* bn1)
{
    const int g = blockIdx.x * 256 + threadIdx.x;
    if (g < 16384)      { int c = s0[g + 1] - s0[g]; atomicAdd(&bn0[c > 63 ? 63 : c], 1); }
    else if (g < 20480) { int r = g - 16384; int c = s1[r + 1] - s1[r]; atomicAdd(&bn1[c > 63 ? 63 : c], 1); }
}

__global__ __launch_bounds__(256)
void sort_scatter(const int* __restrict__ s0, const int* __restrict__ s1,
                  const int* __restrict__ t0, const int* __restrict__ t1,
                  int* bc0, int* bc1, int* ro0, int* ro1)
{
    const int g = blockIdx.x * 256 + threadIdx.x;
    if (g < 16384)      { int c = s0[g + 1] - s0[g]; c = c > 63 ? 63 : c; ro0[t0[c] + atomicAdd(&bc0[c], 1)] = g; }
    else if (g < 20480) { int r = g - 16384; int c = s1[r + 1] - s1[r]; c = c > 63 ? 63 : c; ro1[t1[c] + atomicAdd(&bc1[c], 1)] = r; }
}

// ---------- fused conv+ELU+pool (L0, L1): R parallel rows, sequential edges ----------
template<int CIN, int COUT, int R>
__global__ __launch_bounds__(256)
void fused_conv_pool(const float* __restrict__ xT,   // [NV][CIN][16]
                     const int* __restrict__ idx,    // [NV][9]
                     const int* __restrict__ col, const float* __restrict__ val,
                     const int* __restrict__ start, const int* __restrict__ perm,
                     const int* __restrict__ row_order,
                     const float* __restrict__ W,    // [9*CIN][COUT]
                     const float* __restrict__ bias,
                     float* __restrict__ out)        // [NVOUT][COUT][16]
{
    constexpr int CL = COUT / 4;
    static_assert(R * CL * 2 == 256, "bad geometry");
    constexpr int SLICE  = CIN * 16;
    constexpr int PAD    = (CIN == 3) ? 12 : 4;
    constexpr int STRIDE = SLICE + PAD;
    constexpr int NF4    = R * CIN * 4;
    constexpr int NIT    = (NF4 + 255) / 256;

    __shared__ float xg[R * STRIDE];
    __shared__ int   sv[R][9];
    __shared__ int   srow[R], sstart[R], scnt[R];
    __shared__ float sval[R];

    const int tid = threadIdx.x;
    const int cq = tid % CL;
    const int bh = (tid / CL) & 1;
    const int lr = tid / (CL * 2);

    if (tid < R) {
        int r = row_order[blockIdx.x * R + tid];
        srow[tid] = r;
        int a = start[r];
        sstart[tid] = a; scnt[tid] = start[r + 1] - a;
    }
    __syncthreads();
    const int maxcnt = scnt[R - 1];   // rows cnt-sorted ascending -> last is max

    const float4 bias4 = *(const float4*)(bias + 4 * cq);
    float4 pacc[8];
#pragma unroll
    for (int b = 0; b < 8; ++b) pacc[b] = make_float4(0.f, 0.f, 0.f, 0.f);

    for (int j = 0; j < maxcnt; ++j) {
        if (tid < R) {
            bool vld = j < scnt[tid];
            int e = vld ? perm[sstart[tid] + j] : 0;
            sval[tid] = vld ? val[e] : 0.0f;
            int cv = col[e];
#pragma unroll
            for (int s = 0; s < SEQL; ++s) sv[tid][s] = idx[cv * SEQL + s];
        }
        __syncthreads();

        float4 cacc[8];
#pragma unroll
        for (int b = 0; b < 8; ++b) cacc[b] = bias4;

        for (int s = 0; s < SEQL; ++s) {
#pragma unroll
            for (int it = 0; it < NIT; ++it) {
                int f = tid + it * 256;
                if (NF4 % 256 == 0 || f < NF4) {
                    int fe = f / (CIN * 4), fr = f % (CIN * 4);
                    float4 t = *(const float4*)(xT + (size_t)sv[fe][s] * SLICE + fr * 4);
                    *(float4*)(xg + fe * STRIDE + fr * 4) = t;
                }
            }
            __syncthreads();
            const float* xb = xg + lr * STRIDE + bh * 8;
            const float* Wp = W + (size_t)(s * CIN) * COUT + 4 * cq;

            auto cbody = [&](int c) {
                float4 w  = *(const float4*)(Wp + (size_t)c * COUT);
                float4 x0 = *(const float4*)(xb + c * 16);
                float4 x1 = *(const float4*)(xb + c * 16 + 4);
                fma4(cacc[0], x0.x, w); fma4(cacc[1], x0.y, w);
                fma4(cacc[2], x0.z, w); fma4(cacc[3], x0.w, w);
                fma4(cacc[4], x1.x, w); fma4(cacc[5], x1.y, w);
                fma4(cacc[6], x1.z, w); fma4(cacc[7], x1.w, w);
            };
            if constexpr (CIN <= 8) {
#pragma unroll
                for (int c = 0; c < CIN; ++c) cbody(c);
            } else {
#pragma unroll 2
                for (int c = 0; c < CIN; ++c) cbody(c);
            }
            if (s < SEQL - 1) __syncthreads();   // WAR on xg
        }
        // pool: pacc += val * elu(conv)
        const float vv = sval[lr];
#pragma unroll
        for (int b = 0; b < 8; ++b) {
            float4 y = cacc[b];
            y.x = elu1(y.x); y.y = elu1(y.y); y.z = elu1(y.z); y.w = elu1(y.w);
            fma4(pacc[b], vv, y);
        }
        __syncthreads();   // sval/sv/xg reuse next j
    }

    const int r = srow[lr];
    float* op = out + ((size_t)r * COUT + 4 * cq) * 16 + bh * 8;
#pragma unroll
    for (int i = 0; i < 4; ++i)
#pragma unroll
        for (int q = 0; q < 2; ++q) {
            float4 o = make_float4(getc(pacc[4 * q + 0], i), getc(pacc[4 * q + 1], i),
                                   getc(pacc[4 * q + 2], i), getc(pacc[4 * q + 3], i));
            *(float4*)(op + (size_t)i * 16 + q * 4) = o;
        }
}

// ---------- edge-parallel conv+ELU+scale (L2, L3) -> ye[k][COUT][16] ----------
template<int CIN, int COUT, int EPB>
__global__ __launch_bounds__(256)
void conv_edges(const float* __restrict__ xT, const int* __restrict__ idx,
                const int* __restrict__ col, const float* __restrict__ val,
                const float* __restrict__ W, const float* __restrict__ bias,
                float* __restrict__ ye)
{
    constexpr int CL = COUT / 4;
    static_assert(EPB * CL == 256, "bad geometry");
    constexpr int SLICE  = CIN * 16;
    constexpr int STRIDE = CIN * 8 + 4;
    constexpr int NF4    = EPB * CIN * 2;
    constexpr int NIT    = (NF4 + 255) / 256;

    __shared__ float xg[EPB * STRIDE];
    __shared__ int   sv[EPB][9];

    const int tid = threadIdx.x;
    const int cq = tid % CL;
    const int e  = tid / CL;
    const int k0 = blockIdx.x * EPB;
    const int bh0 = blockIdx.y * 8;

    if (tid < EPB) {
        int cv = col[k0 + tid];
#pragma unroll
        for (int s = 0; s < SEQL; ++s) sv[tid][s] = idx[cv * SEQL + s];
    }
    __syncthreads();

    const float4 bias4 = *(const float4*)(bias + 4 * cq);
    float4 cacc[8];
#pragma unroll
    for (int b = 0; b < 8; ++b) cacc[b] = bias4;

    for (int s = 0; s < SEQL; ++s) {
#pragma unroll
        for (int it = 0; it < NIT; ++it) {
            int f = tid + it * 256;
            if (NF4 % 256 == 0 || f < NF4) {
                int fe = f / (CIN * 2), fr = f % (CIN * 2);
                int c = fr >> 1, q = fr & 1;
                float4 t = *(const float4*)(xT + (size_t)sv[fe][s] * SLICE + c * 16 + bh0 + q * 4);
                *(float4*)(xg + fe * STRIDE + fr * 4) = t;
            }
        }
        __syncthreads();
        const float* xb = xg + e * STRIDE;
        const float* Wp = W + (size_t)(s * CIN) * COUT + 4 * cq;

        auto cbody = [&](int c) {
            float4 w  = *(const float4*)(Wp + (size_t)c * COUT);
            float4 x0 = *(const float4*)(xb + c * 8);
            float4 x1 = *(const float4*)(xb + c * 8 + 4);
            fma4(cacc[0], x0.x, w); fma4(cacc[1], x0.y, w);
            fma4(cacc[2], x0.z, w); fma4(cacc[3], x0.w, w);
            fma4(cacc[4], x1.x, w); fma4(cacc[5], x1.y, w);
            fma4(cacc[6], x1.z, w); fma4(cacc[7], x1.w, w);
        };
#pragma unroll 2
        for (int c = 0; c < CIN; ++c) cbody(c);

        if (s < SEQL - 1) __syncthreads();
    }

    const float vv = val[k0 + e];
#pragma unroll
    for (int b = 0; b < 8; ++b) {
        float4 y = cacc[b];
        cacc[b] = make_float4(vv * elu1(y.x), vv * elu1(y.y), vv * elu1(y.z), vv * elu1(y.w));
    }
    float* yp = ye + ((size_t)(k0 + e) * COUT + 4 * cq) * 16 + bh0;
#pragma unroll
    for (int i = 0; i < 4; ++i)
#pragma unroll
        for (int q = 0; q < 2; ++q) {
            float4 o = make_float4(getc(cacc[4 * q + 0], i), getc(cacc[4 * q + 1], i),
                                   getc(cacc[4 * q + 2], i), getc(cacc[4 * q + 3], i));
            *(float4*)(yp + (size_t)i * 16 + q * 4) = o;
        }
}

// ---------- CSR gather pool (L2, L3): out[r] = sum_j ye[perm[j]] ----------
template<int COUT>
__global__ __launch_bounds__(256)
void pool_gather(const float* __restrict__ ye, const int* __restrict__ start,
                 const int* __restrict__ perm, float* __restrict__ out)
{
    constexpr int RW = COUT * 4;   // float4s per out row
    const int pos = blockIdx.x * 256 + threadIdx.x;
    const int r = pos / RW, o = pos % RW;
    const int lo = start[r], hi = start[r + 1];
    float4 a = make_float4(0.f, 0.f, 0.f, 0.f);
    for (int j = lo; j < hi; ++j) {
        int e = perm[j];
        float4 y = *(const float4*)(ye + (size_t)e * RW * 4 + o * 4);
        a.x += y.x; a.y += y.y; a.z += y.z; a.w += y.w;   // val already folded into ye
    }
    *(float4*)(out + (size_t)r * RW * 4 + o * 4) = a;
}

// ---------- final GEMM ----------
__global__ __launch_bounds__(256)
void final_gemm_partial(const float* __restrict__ x4T,  // [65536][16]
                        const float* __restrict__ Wf,   // [65536][256]
                        float* __restrict__ part)       // [256][16][256]
{
    __shared__ float xs[256 * 16];
    const int j0 = blockIdx.x * 256;
    const int t  = threadIdx.x;
#pragma unroll
    for (int it = 0; it < 4; ++it) {
        const int f = t + it * 256;
        *(float4*)(xs + f * 4) = *(const float4*)(x4T + (size_t)j0 * 16 + f * 4);
    }
    __syncthreads();

    float acc[16];
#pragma unroll
    for (int b = 0; b < 16; ++b) acc[b] = 0.0f;
#pragma unroll 4
    for (int jj = 0; jj < 256; ++jj) {
        const float w = Wf[(size_t)(j0 + jj) * 256 + t];
#pragma unroll
        for (int b4 = 0; b4 < 4; ++b4) {
            const float4 xv = *(const float4*)(xs + jj * 16 + b4 * 4);
            acc[b4 * 4 + 0] = fmaf(xv.x, w, acc[b4 * 4 + 0]);
            acc[b4 * 4 + 1] = fmaf(xv.y, w, acc[b4 * 4 + 1]);
            acc[b4 * 4 + 2] = fmaf(xv.z, w, acc[b4 * 4 + 2]);
            acc[b4 * 4 + 3] = fmaf(xv.w, w, acc[b4 * 4 + 3]);
        }
    }
#pragma unroll
    for (int b = 0; b < 16; ++b)
        part[(size_t)blockIdx.x * 4096 + b * 256 + t] = acc[b];
}

__global__ __launch_bounds__(256)
void final_reduce(const float* __restrict__ part, const float* __restrict__ bf,
                  float* __restrict__ out)
{
    const int b = blockIdx.x, l = threadIdx.x;
    float s = 0.0f;
    for (int jb = 0; jb < 256; ++jb) s += part[(size_t)jb * 4096 + b * 256 + l];
    out[b * 256 + l] = s + bf[l];
}

// ---------- launch ----------
extern "C" void kernel_launch(void* const* d_in, const int* in_sizes, int n_in,
                              void* d_out, int out_size, void* d_ws, size_t ws_size,
                              hipStream_t stream)
{
    const float* x    = (const float*)d_in[0];
    const int*   idx0 = (const int*)d_in[1];
    const int*   row0 = (const int*)d_in[2];
    const int*   col0 = (const int*)d_in[3];
    const float* val0 = (const float*)d_in[4];
    const float* W0   = (const float*)d_in[5];
    const float* b0   = (const float*)d_in[6];
    const int*   idx1 = (const int*)d_in[7];
    const int*   row1 = (const int*)d_in[8];
    const int*   col1 = (const int*)d_in[9];
    const float* val1 = (const float*)d_in[10];
    const float* W1   = (const float*)d_in[11];
    const float* b1   = (const float*)d_in[12];
    const int*   idx2 = (const int*)d_in[13];
    const int*   row2 = (const int*)d_in[14];
    const int*   col2 = (const int*)d_in[15];
    const float* val2 = (const float*)d_in[16];
    const float* W2   = (const float*)d_in[17];
    const float* b2   = (const float*)d_in[18];
    const int*   idx3 = (const int*)d_in[19];
    const int*   row3 = (const int*)d_in[20];
    const int*   col3 = (const int*)d_in[21];
    const float* val3 = (const float*)d_in[22];
    const float* W3   = (const float*)d_in[23];
    const float* b3   = (const float*)d_in[24];
    const float* Wf   = (const float*)d_in[25];
    const float* bf   = (const float*)d_in[26];
    float* out = (float*)d_out;

    float* ws = (float*)d_ws;
    // activation aliasing (float offsets), lifetimes verified disjoint:
    float* x1T = ws + 0;          // [16384][32][16]  P1-P2
    float* xT0 = ws + 8388608;    // [65536][3][16]   P0-P1
    float* x2T = ws + 8388608;    // [4096][64][16]   P2-P3 (over dead xT0)
    float* ye2 = ws + 0;          // [3072][128][16]  P3-P4 (over dead x1T)
    float* x3T = ws + 6291456;    // [1024][128][16]  P4-P5
    float* ye3 = ws + 0;          // [768][256][16]   P5-P6
    float* x4T = ws + 3145728;    // [256][256][16]   P6-P7
    float* part= ws + 4194304;    // [256][16][256]   P7

    int* csr = (int*)(ws + 12582912);
    int *c0 = csr +      0, *c1 = csr + 16384, *c2 = csr + 20480, *c3 = csr + 21504;
    int *u0 = csr +  21760, *u1 = csr + 38144, *u2 = csr + 42240, *u3 = csr + 43264;
    int *bn0= csr +  43520, *bn1= csr + 43584;
    int *bc0= csr +  43648, *bc1= csr + 43712;
    int *s0 = csr +  43776, *s1 = csr + 60161, *s2 = csr + 64258, *s3 = csr + 65283;
    int *t0 = csr +  65540, *t1 = csr + 65605;
    int *p0 = csr +  65670, *p1 = csr + 114822, *p2 = csr + 127110, *p3 = csr + 130182;
    int *ro0= csr + 130950, *ro1= csr + 147334;

    // zero counts/cursors/bins/bincursors in one memset
    hipMemsetAsync(csr, 0, (size_t)43776 * sizeof(int), stream);

    transpose_x0<<<12288, 256, 0, stream>>>(x, xT0);

    hist_edges<<<255, 256, 0, stream>>>(row0, row1, row2, row3, c0, c1, c2, c3);

    ScanTasks T;
    T.in[0]=c0; T.out[0]=s0; T.n[0]=16384;
    T.in[1]=c1; T.out[1]=s1; T.n[1]=4096;
    T.in[2]=c2; T.out[2]=s2; T.n[2]=1024;
    T.in[3]=c3; T.out[3]=s3; T.n[3]=256;
    T.in[4]=bn0;T.out[4]=t0; T.n[4]=64;
    T.in[5]=bn1;T.out[5]=t1; T.n[5]=64;
    scan_multi<<<4, 256, 0, stream>>>(T, 0);

    scatter_edges<<<255, 256, 0, stream>>>(row0, row1, row2, row3,
                                           s0, s1, s2, s3, u0, u1, u2, u3,
                                           p0, p1, p2, p3);
    sort_hist<<<80, 256, 0, stream>>>(s0, s1, bn0, bn1);
    scan_multi<<<2, 256, 0, stream>>>(T, 4);
    sort_scatter<<<80, 256, 0, stream>>>(s0, s1, t0, t1, bc0, bc1, ro0, ro1);

    // L0: xT0 -> x1T
    fused_conv_pool<3, 32, 16><<<1024, 256, 0, stream>>>(
        xT0, idx0, col0, val0, s0, p0, ro0, W0, b0, x1T);
    // L1: x1T -> x2T
    fused_conv_pool<32, 64, 8><<<512, 256, 0, stream>>>(
        x1T, idx1, col1, val1, s1, p1, ro1, W1, b1, x2T);
    // L2: x2T -> ye2 -> x3T
    conv_edges<64, 128, 8><<<dim3(384, 2), 256, 0, stream>>>(
        x2T, idx2, col2, val2, W2, b2, ye2);
    pool_gather<128><<<2048, 256, 0, stream>>>(ye2, s2, p2, x3T);
    // L3: x3T -> ye3 -> x4T
    conv_edges<128, 256, 4><<<dim3(192, 2), 256, 0, stream>>>(
        x3T, idx3, col3, val3, W3, b3, ye3);
    pool_gather<256><<<1024, 256, 0, stream>>>(ye3, s3, p3, x4T);

    // final GEMM
    final_gemm_partial<<<256, 256, 0, stream>>>(x4T, Wf, part);
    final_reduce<<<16, 256, 0, stream>>>(part, bf, out);
}

// Round 5
// 555.885 us; speedup vs baseline: 7.9060x; 2.0792x over previous
//
#include <hip/hip_runtime.h>
#include <math.h>

// Mesh encoder: 4x (spiral conv + ELU + sparse pool) + final GEMM.
// VERTS = [65536, 16384, 4096, 1024, 256], SEQ=9, CH=[3,32,64,128,256], B=16.
//
// R5: wave-per-edge MFMA conv (16x16x32 bf16, M=16 batches), 3-MFMA hi/lo
// error split for fp32-class accuracy, direct atomic pool-scatter in
// [b][r][co] layout (lane-contiguous), no CSR, no LDS, no barriers.

#define SEQL 9

typedef __attribute__((ext_vector_type(8))) short bf16x8;
typedef __attribute__((ext_vector_type(4))) float f32x4;

__device__ __forceinline__ unsigned short f2bf_rne(float f) {
    unsigned u = __builtin_bit_cast(unsigned, f);
    u = (u + 0x7FFFu + ((u >> 16) & 1u)) >> 16;
    return (unsigned short)u;
}
__device__ __forceinline__ float bf2f(unsigned short h) {
    unsigned u = ((unsigned)h) << 16;
    return __builtin_bit_cast(float, u);
}

// x [16][65536][3] -> xT [65536][3][16]  (L0 A-gather coalescing: 16 batches
// of one (v,c) sit in one 64B line)
__global__ __launch_bounds__(256)
void transpose_x0(const float* __restrict__ x, float* __restrict__ xT)
{
    const int f = blockIdx.x * 256 + threadIdx.x;   // 65536*48
    const int v = f / 48, rem = f % 48;
    const int c = rem / 16, b = rem % 16;
    xT[f] = x[((size_t)b * 65536 + v) * 3 + c];
}

// W [9*CIN][COUT] fp32 -> WTh/WTl [COUT][K] bf16 (K padded to mult of 32,
// pad rows zero; lo = W - hi for the error-split).
template<int CIN, int COUT>
__global__ __launch_bounds__(256)
void wt_prep(const float* __restrict__ W, unsigned short* __restrict__ WTh,
             unsigned short* __restrict__ WTl)
{
    constexpr int K9 = 9 * CIN;
    constexpr int K  = ((K9 + 31) / 32) * 32;
    const int t = blockIdx.x * 256 + threadIdx.x;   // COUT*K total, exact grid
    const int co = t / K, k = t % K;
    float w = (k < K9) ? W[(size_t)k * COUT + co] : 0.0f;
    unsigned short h = f2bf_rne(w);
    WTh[t] = h;
    WTl[t] = f2bf_rne(w - bf2f(h));
}

// One wave per pooling edge e: compute conv(col[e]) for all 16 batches via
// MFMA (A rows = batches, B cols = couts), ELU, scale by val[e], atomicAdd
// into xout[b][row[e]][co].
// xin layout: CIN>=32: [16][NV][CIN] batch-major; CIN==3: [NV][3][16].
template<int CIN, int COUT>
__global__ __launch_bounds__(256)
void conv_pool_mfma(const float* __restrict__ xin,
                    const int* __restrict__ idx,    // [NV][9]
                    const int* __restrict__ col, const int* __restrict__ row,
                    const float* __restrict__ val,
                    const unsigned short* __restrict__ WTh,
                    const unsigned short* __restrict__ WTl,
                    const float* __restrict__ bias,
                    float* __restrict__ xout,       // [16][NVOUT][COUT], zeroed
                    int NV, int NVOUT, int nnz)
{
    constexpr int K9 = 9 * CIN;
    constexpr int KSTEPS = (K9 + 31) / 32;
    constexpr int K = KSTEPS * 32;
    constexpr int NT = COUT / 16;

    const int lane = threadIdx.x & 63;
    const int wid  = threadIdx.x >> 6;
    const int e    = blockIdx.x * 4 + wid;
    if (e >= nnz) return;

    const int   v  = col[e];
    const int   r  = row[e];
    const float vv = val[e];
    const int b16 = lane & 15;   // A row (batch) / B col (co_local)
    const int g   = lane >> 4;   // k-slot group

    f32x4 acc[NT];
#pragma unroll
    for (int nt = 0; nt < NT; ++nt) {
        const float bv = bias[nt * 16 + b16];   // C[row][col]=bias[col], all rows
        acc[nt] = (f32x4){bv, bv, bv, bv};
    }

#pragma unroll 1
    for (int ks = 0; ks < KSTEPS; ++ks) {
        bf16x8 ah, al;
        if constexpr (CIN >= 32) {
            constexpr int KPS = CIN / 32;
            const int s  = ks / KPS;
            const int c0 = (ks % KPS) * 32 + g * 8;
            const int vi = idx[v * SEQL + s];
            const float* xp = xin + ((size_t)b16 * NV + vi) * CIN + c0;
            const float4 x0 = *(const float4*)xp;
            const float4 x1 = *(const float4*)(xp + 4);
            const float xf[8] = {x0.x, x0.y, x0.z, x0.w, x1.x, x1.y, x1.z, x1.w};
#pragma unroll
            for (int j = 0; j < 8; ++j) {
                const unsigned short h = f2bf_rne(xf[j]);
                ah[j] = (short)h;
                al[j] = (short)f2bf_rne(xf[j] - bf2f(h));
            }
        } else {
            // CIN==3, K9=27: slots k>=27 are zero-padded (WT pad rows are 0 too)
#pragma unroll
            for (int j = 0; j < 8; ++j) {
                const int k = g * 8 + j;
                float xf = 0.0f;
                if (k < K9) {
                    const int s = k / 3;
                    const int c = k - 3 * s;
                    const int vi = idx[v * SEQL + s];
                    xf = xin[(size_t)vi * 48 + c * 16 + b16];
                }
                const unsigned short h = f2bf_rne(xf);
                ah[j] = (short)h;
                al[j] = (short)f2bf_rne(xf - bf2f(h));
            }
        }
#pragma unroll
        for (int nt = 0; nt < NT; ++nt) {
            const size_t wo = (size_t)(nt * 16 + b16) * K + ks * 32 + g * 8;
            const bf16x8 bh = *(const bf16x8*)(WTh + wo);
            const bf16x8 bl = *(const bf16x8*)(WTl + wo);
            // (ah+al)*(bh+bl) ~= ah*bh + al*bh + ah*bl  (al*bl ~ 2e-5, dropped)
            acc[nt] = __builtin_amdgcn_mfma_f32_16x16x32_bf16(ah, bh, acc[nt], 0, 0, 0);
            acc[nt] = __builtin_amdgcn_mfma_f32_16x16x32_bf16(al, bh, acc[nt], 0, 0, 0);
            acc[nt] = __builtin_amdgcn_mfma_f32_16x16x32_bf16(ah, bl, acc[nt], 0, 0, 0);
        }
    }

    // D: row=(lane>>4)*4+reg (batch), col=lane&15 (co_local) [m89-verified]
#pragma unroll
    for (int nt = 0; nt < NT; ++nt)
#pragma unroll
        for (int q = 0; q < 4; ++q) {
            const int b = g * 4 + q;
            float y = acc[nt][q];
            y = (y > 0.0f) ? y : __expf(y) - 1.0f;
            atomicAdd(xout + ((size_t)b * NVOUT + r) * COUT + nt * 16 + b16, vv * y);
        }
}

// Final GEMM partials: part[jblk][b][l] = sum_{j in blk} x4[b][j]*Wf[j][l]
// x4 is batch-major [16][65536]; stage transposed into LDS (stride 20: 16B
// aligned float4 rows, conflict-light writes, broadcast reads).
__global__ __launch_bounds__(256)
void final_gemm_partial(const float* __restrict__ x4,   // [16][65536]
                        const float* __restrict__ Wf,   // [65536][256]
                        float* __restrict__ part)       // [256][16][256]
{
    __shared__ float xs[256 * 20];
    const int j0 = blockIdx.x * 256;
    const int t  = threadIdx.x;

#pragma unroll
    for (int it = 0; it < 16; ++it)
        xs[t * 20 + it] = x4[(size_t)it * 65536 + j0 + t];
    __syncthreads();

    float acc[16];
#pragma unroll
    for (int b = 0; b < 16; ++b) acc[b] = 0.0f;

#pragma unroll 4
    for (int jj = 0; jj < 256; ++jj) {
        const float w = Wf[(size_t)(j0 + jj) * 256 + t];
#pragma unroll
        for (int b4 = 0; b4 < 4; ++b4) {
            const float4 xv = *(const float4*)(xs + jj * 20 + b4 * 4);
            acc[b4 * 4 + 0] = fmaf(xv.x, w, acc[b4 * 4 + 0]);
            acc[b4 * 4 + 1] = fmaf(xv.y, w, acc[b4 * 4 + 1]);
            acc[b4 * 4 + 2] = fmaf(xv.z, w, acc[b4 * 4 + 2]);
            acc[b4 * 4 + 3] = fmaf(xv.w, w, acc[b4 * 4 + 3]);
        }
    }
#pragma unroll
    for (int b = 0; b < 16; ++b)
        part[(size_t)blockIdx.x * 4096 + b * 256 + t] = acc[b];
}

__global__ __launch_bounds__(256)
void final_reduce(const float* __restrict__ part, const float* __restrict__ bf,
                  float* __restrict__ out)
{
    const int b = blockIdx.x, l = threadIdx.x;   // 16 x 256
    float s = 0.0f;
    for (int jb = 0; jb < 256; ++jb) s += part[(size_t)jb * 4096 + b * 256 + l];
    out[b * 256 + l] = s + bf[l];
}

extern "C" void kernel_launch(void* const* d_in, const int* in_sizes, int n_in,
                              void* d_out, int out_size, void* d_ws, size_t ws_size,
                              hipStream_t stream)
{
    const float* x    = (const float*)d_in[0];
    const int*   idx0 = (const int*)d_in[1];
    const int*   row0 = (const int*)d_in[2];
    const int*   col0 = (const int*)d_in[3];
    const float* val0 = (const float*)d_in[4];
    const float* W0   = (const float*)d_in[5];
    const float* b0   = (const float*)d_in[6];
    const int*   idx1 = (const int*)d_in[7];
    const int*   row1 = (const int*)d_in[8];
    const int*   col1 = (const int*)d_in[9];
    const float* val1 = (const float*)d_in[10];
    const float* W1   = (const float*)d_in[11];
    const float* b1   = (const float*)d_in[12];
    const int*   idx2 = (const int*)d_in[13];
    const int*   row2 = (const int*)d_in[14];
    const int*   col2 = (const int*)d_in[15];
    const float* val2 = (const float*)d_in[16];
    const float* W2   = (const float*)d_in[17];
    const float* b2   = (const float*)d_in[18];
    const int*   idx3 = (const int*)d_in[19];
    const int*   row3 = (const int*)d_in[20];
    const int*   col3 = (const int*)d_in[21];
    const float* val3 = (const float*)d_in[22];
    const float* W3   = (const float*)d_in[23];
    const float* b3   = (const float*)d_in[24];
    const float* Wf   = (const float*)d_in[25];
    const float* bf   = (const float*)d_in[26];
    float* out = (float*)d_out;

    float* ws = (float*)d_ws;
    // Aliased timeline (float offsets), peak 51.9 MB:
    float* x1   = ws + 0;         // [16][16384][32]  live L0->L1
    float* xT0  = ws + 8388608;   // [65536][3][16]   live pre->L0
    float* x2   = ws + 8388608;   // [16][4096][64]   live L1->L2 (zeroed post-L0)
    float* x3   = ws + 0;         // [16][1024][128]  live L2->L3 (zeroed post-L1)
    float* x4   = ws + 2097152;   // [16][256][256]   live L3->final
    float* part = ws + 3145728;   // [256][16][256]   final phase
    unsigned short* wt = (unsigned short*)(ws + 12582912);
    unsigned short *WTh0 = wt,            *WTl0 = wt + 1024;
    unsigned short *WTh1 = wt + 2048,     *WTl1 = wt + 20480;
    unsigned short *WTh2 = wt + 38912,    *WTl2 = wt + 112640;
    unsigned short *WTh3 = wt + 186368,   *WTl3 = wt + 481280;   // end 776192 u16

    // weight prep (tiny)
    wt_prep<3,   32><<<   4, 256, 0, stream>>>(W0, WTh0, WTl0);
    wt_prep<32,  64><<<  72, 256, 0, stream>>>(W1, WTh1, WTl1);
    wt_prep<64, 128><<< 288, 256, 0, stream>>>(W2, WTh2, WTl2);
    wt_prep<128,256><<<1152, 256, 0, stream>>>(W3, WTh3, WTl3);

    // L0
    hipMemsetAsync(x1, 0, (size_t)8388608 * 4, stream);
    transpose_x0<<<12288, 256, 0, stream>>>(x, xT0);
    conv_pool_mfma<3, 32><<<12288, 256, 0, stream>>>(
        xT0, idx0, col0, row0, val0, WTh0, WTl0, b0, x1, 65536, 16384, 49152);

    // L1
    hipMemsetAsync(x2, 0, (size_t)4194304 * 4, stream);   // xT0 dead
    conv_pool_mfma<32, 64><<<3072, 256, 0, stream>>>(
        x1, idx1, col1, row1, val1, WTh1, WTl1, b1, x2, 16384, 4096, 12288);

    // L2 + L3 (x1 dead -> zero x3|x4 region in one go)
    hipMemsetAsync(x3, 0, (size_t)3145728 * 4, stream);
    conv_pool_mfma<64, 128><<<768, 256, 0, stream>>>(
        x2, idx2, col2, row2, val2, WTh2, WTl2, b2, x3, 4096, 1024, 3072);
    conv_pool_mfma<128, 256><<<192, 256, 0, stream>>>(
        x3, idx3, col3, row3, val3, WTh3, WTl3, b3, x4, 1024, 256, 768);

    // final GEMM: out[16,256] = bf + x4_flat[16,65536] @ Wf[65536,256]
    final_gemm_partial<<<256, 256, 0, stream>>>(x4, Wf, part);
    final_reduce<<<16, 256, 0, stream>>>(part, bf, out);
}